// Round 5
// baseline (941.861 us; speedup 1.0000x reference)
//
#include <hip/hip_runtime.h>
#include <hip/hip_bf16.h>
#include <stdint.h>

typedef __attribute__((ext_vector_type(8))) short s16x8;           // MFMA A/B frag: 8 bf16
typedef __attribute__((ext_vector_type(4))) float f32x4;           // MFMA C/D frag / fp32 vec4
typedef __attribute__((ext_vector_type(8))) unsigned short u16x8;  // 16B vector

__device__ __forceinline__ float bf2f(unsigned short u) {
  union { uint32_t u; float f; } v; v.u = ((uint32_t)u) << 16; return v.f;
}
__device__ __forceinline__ unsigned short f2bf(float f) {
  union { float f; uint32_t u; } v; v.f = f;
  uint32_t u = v.u;
  return (unsigned short)((u + 0x7fffu + ((u >> 16) & 1u)) >> 16);  // RNE
}
__device__ __forceinline__ void load_lds16(const void* g, void* l) {
  __builtin_amdgcn_global_load_lds(
      (const __attribute__((address_space(1))) void*)g,
      (__attribute__((address_space(3))) void*)l, 16, 0, 0);
}

// ---------------------------------------------------------------------------
// D0: dtype sniff (fp32 inputs -> flag=1). Confirmed working (NaN vanished
// when conversion landed in r3).
// ---------------------------------------------------------------------------
__global__ void k_detect(const uint32_t* __restrict__ xw, int* __restrict__ flag) {
  int lane = threadIdx.x;  // 64 threads
  uint32_t u = xw[lane * 97 + 1];
  int e = (u >> 7) & 0xFF;
  unsigned long long m = __ballot(e > 150);
  if (lane == 0) *flag = (__popcll(m) > 6) ? 1 : 0;
}

// ---------------------------------------------------------------------------
// T0: x (3072 w x 4096 m) -> Xt (4096 m x 3072 w) bf16
// ---------------------------------------------------------------------------
__global__ __launch_bounds__(256) void k_transpose(const void* __restrict__ xin,
                                                   unsigned short* __restrict__ xt,
                                                   const int* __restrict__ flag) {
  __shared__ __align__(16) unsigned short tile[64 * 65];
  const int t = threadIdx.x;
  const int w0 = blockIdx.x * 64;
  const int m0 = blockIdx.y * 64;
  if (*flag) {
    const float* xf = (const float*)xin;
#pragma unroll
    for (int rep = 0; rep < 4; ++rep) {
      int vi = t + rep * 256;
      int r = vi >> 4;
      int c4 = (vi & 15) * 4;
      f32x4 v = *(const f32x4*)(xf + (uint64_t)(w0 + r) * 4096 + m0 + c4);
#pragma unroll
      for (int u = 0; u < 4; ++u) tile[(c4 + u) * 65 + r] = f2bf(v[u]);
    }
  } else {
    const unsigned short* xb = (const unsigned short*)xin;
#pragma unroll
    for (int rep = 0; rep < 2; ++rep) {
      int vi = t + rep * 256;
      int r = vi >> 3;
      int c8 = (vi & 7) * 8;
      u16x8 v = *(const u16x8*)(xb + (uint64_t)(w0 + r) * 4096 + m0 + c8);
#pragma unroll
      for (int u = 0; u < 8; ++u) tile[(c8 + u) * 65 + r] = v[u];
    }
  }
  __syncthreads();
#pragma unroll
  for (int rep = 0; rep < 2; ++rep) {
    int vi = t + rep * 256;
    int r = vi >> 3;
    int c8 = (vi & 7) * 8;
    u16x8 v;
#pragma unroll
    for (int u = 0; u < 8; ++u) v[u] = tile[r * 65 + c8 + u];
    *(u16x8*)(xt + (uint64_t)(m0 + r) * 3072 + w0 + c8) = v;
  }
}

// ---------------------------------------------------------------------------
// A -> Ab bf16
// ---------------------------------------------------------------------------
__global__ __launch_bounds__(256) void k_cvtA(const void* __restrict__ Ain,
                                              unsigned short* __restrict__ Ab,
                                              const int* __restrict__ flag) {
  uint64_t i = ((uint64_t)blockIdx.x * 256 + threadIdx.x) * 8;
  if (*flag) {
    const float* Af = (const float*)Ain;
    f32x4 a = *(const f32x4*)(Af + i);
    f32x4 b = *(const f32x4*)(Af + i + 4);
    u16x8 o;
#pragma unroll
    for (int u = 0; u < 4; ++u) { o[u] = f2bf(a[u]); o[u + 4] = f2bf(b[u]); }
    *(u16x8*)(Ab + i) = o;
  } else {
    *(u16x8*)(Ab + i) = *(const u16x8*)((const unsigned short*)Ain + i);
  }
}

// ---------------------------------------------------------------------------
// W0,b0,W1,b1 -> contiguous bf16 block wb[16640]
// ---------------------------------------------------------------------------
__global__ __launch_bounds__(256) void k_cvtW(const void* __restrict__ W0,
                                              const void* __restrict__ b0,
                                              const void* __restrict__ W1,
                                              const void* __restrict__ b1,
                                              unsigned short* __restrict__ wb,
                                              const int* __restrict__ flag) {
  int fp = *flag;
  for (int i = threadIdx.x; i < 16640; i += 256) {
    const void* src; int off;
    if (i < 8192)        { src = W0; off = i; }
    else if (i < 8320)   { src = b0; off = i - 8192; }
    else if (i < 16512)  { src = W1; off = i - 8320; }
    else                 { src = b1; off = i - 16512; }
    wb[i] = fp ? f2bf(((const float*)src)[off]) : ((const unsigned short*)src)[off];
  }
}

// ---------------------------------------------------------------------------
// NT GEMM: C[v][m] = sum_k Am[v][k] * Bm[m][k]; C ld = 4096, bf16 out.
// m97-lineage K-loop; direct scalar global-store epilogue.
// ---------------------------------------------------------------------------
template <int BM>
__global__ __launch_bounds__(256) void k_gemm_nt(const unsigned short* __restrict__ Am,
                                                 const unsigned short* __restrict__ Bm,
                                                 unsigned short* __restrict__ Cm,
                                                 int K) {
  constexpr int IF = BM / 32;
  __shared__ __align__(16) unsigned short smem[BM * 64 + 128 * 64];
  unsigned short* At = smem;                     // [BM][64]
  unsigned short* Bt = smem + BM * 64;           // [128][64]

  const int t = threadIdx.x;
  const int lane = t & 63;
  const int wid = t >> 6;
  const int wV = wid >> 1;
  const int wM = wid & 1;
  const int v0 = blockIdx.x * BM;
  const int m0 = blockIdx.y * 128;

  f32x4 acc[IF][4] = {};

  const int arow = wid * (BM / 4) + (lane >> 3);
  const int brow = wid * 32 + (lane >> 3);
  const int scol = (lane & 7) * 8;
  const unsigned short* gA = Am + (uint64_t)(v0 + arow) * K + scol;
  const unsigned short* gB = Bm + (uint64_t)(m0 + brow) * K + scol;
  unsigned short* lA = At + wid * (BM / 4) * 64;
  unsigned short* lB = Bt + wid * 32 * 64;

  const int fr = lane & 15;
  const int fk = (lane >> 4) * 8;

  for (int kk = 0; kk < K; kk += 64) {
    __syncthreads();
#pragma unroll
    for (int q = 0; q < BM / 32; ++q)
      load_lds16(gA + (uint64_t)(q * 8) * K + kk, lA + q * 8 * 64);
#pragma unroll
    for (int q = 0; q < 4; ++q)
      load_lds16(gB + (uint64_t)(q * 8) * K + kk, lB + q * 8 * 64);
    __syncthreads();
#pragma unroll
    for (int ks = 0; ks < 64; ks += 32) {
      s16x8 af[IF], bf[4];
#pragma unroll
      for (int i = 0; i < IF; ++i)
        af[i] = *(const s16x8*)(At + (wV * (BM / 2) + i * 16 + fr) * 64 + ks + fk);
#pragma unroll
      for (int j = 0; j < 4; ++j)
        bf[j] = *(const s16x8*)(Bt + (wM * 64 + j * 16 + fr) * 64 + ks + fk);
#pragma unroll
      for (int i = 0; i < IF; ++i)
#pragma unroll
        for (int j = 0; j < 4; ++j)
          acc[i][j] = __builtin_amdgcn_mfma_f32_16x16x32_bf16(af[i], bf[j], acc[i][j], 0, 0, 0);
    }
  }

  // direct-store epilogue: C/D map col=lane&15, row=(lane>>4)*4+reg [m89/m91]
  const int rr = (lane >> 4) * 4;
#pragma unroll
  for (int i = 0; i < IF; ++i) {
    int vbase = v0 + wV * (BM / 2) + i * 16 + rr;
#pragma unroll
    for (int j = 0; j < 4; ++j) {
      int m = m0 + wM * 64 + j * 16 + fr;
#pragma unroll
      for (int r = 0; r < 4; ++r)
        Cm[(uint64_t)(vbase + r) * 4096 + m] = f2bf(acc[i][j][r]);
    }
  }
}

// ---------------------------------------------------------------------------
// Simple VALU GLU: one thread per (v,o) pair (per b). grid (Vtot/4, B),
// block 256 = 4 v x 64 o.  H[(b*64+o)*Vtot + v] = y0 * sigmoid(y1).
// ---------------------------------------------------------------------------
__global__ __launch_bounds__(256) void k_glu_simple(const unsigned short* __restrict__ G,
                                                    const unsigned short* __restrict__ W,
                                                    const unsigned short* __restrict__ bias,
                                                    unsigned short* __restrict__ H,
                                                    int Vtot) {
  const int t = threadIdx.x;
  const int o = t & 63;
  const int v = blockIdx.x * 4 + (t >> 6);
  const int b = blockIdx.y;
  const unsigned short* g = G + (uint64_t)v * 4096 + b * 64;
  const unsigned short* w0r = W + o * 64;
  const unsigned short* w1r = W + (o + 64) * 64;
  float y0 = bf2f(bias[o]);
  float y1 = bf2f(bias[o + 64]);
#pragma unroll 8
  for (int c = 0; c < 64; ++c) {
    float gv = bf2f(g[c]);
    y0 += bf2f(w0r[c]) * gv;
    y1 += bf2f(w1r[c]) * gv;
  }
  float h = y0 / (1.0f + __expf(-y1));
  H[(uint64_t)(b * 64 + o) * Vtot + v] = f2bf(h);
}

// ---------------------------------------------------------------------------
// Simple scalar maxout, fp32 OUTPUT:
// out[n*4096 + b*64 + j] = max(H1[bj][1024+n], H2[bj][n])
// ---------------------------------------------------------------------------
__global__ __launch_bounds__(256) void k_max_simple(const unsigned short* __restrict__ H1,
                                                    const unsigned short* __restrict__ H2,
                                                    float* __restrict__ out) {
  uint32_t idx = blockIdx.x * 256 + threadIdx.x;  // < 4194304
  int n = idx >> 12;
  int bj = idx & 4095;
  float a = bf2f(H1[(uint64_t)bj * 3072 + 1024 + n]);
  float c = bf2f(H2[(uint64_t)bj * 1024 + n]);
  out[idx] = fmaxf(a, c);
}

// ---------------------------------------------------------------------------
extern "C" void kernel_launch(void* const* d_in, const int* in_sizes, int n_in,
                              void* d_out, int out_size, void* d_ws, size_t ws_size,
                              hipStream_t stream) {
  (void)in_sizes; (void)n_in; (void)out_size; (void)ws_size;
  const void* x  = d_in[0];  // [3072][64][64]
  const void* A  = d_in[1];  // [3072][3072]
  const void* W0 = d_in[2];  // [128][64]
  const void* b0 = d_in[3];  // [128]
  const void* W1 = d_in[4];  // [128][64]
  const void* b1 = d_in[5];  // [128]
  float* out = (float*)d_out;  // [1024][64][64] fp32 (reference output dtype)

  char* ws = (char*)d_ws;
  unsigned short* Xt  = (unsigned short*)(ws + 0);         // 25165824 B
  unsigned short* Ab  = (unsigned short*)(ws + 25165824);  // 18874368 B
  unsigned short* Wb  = (unsigned short*)(ws + 44040192);  // 33280 B
  unsigned short* Gt  = (unsigned short*)(ws + 44105728);  // 25165824 B
  unsigned short* H1  = (unsigned short*)(ws + 0);         // overlays Xt (dead after K1)
  unsigned short* Gt2 = (unsigned short*)(ws + 44105728);  // overlays Gt (dead after K2)
  unsigned short* H2  = (unsigned short*)(ws + 52494336);  // 8388608 B
  int* flag = (int*)(ws + 69271552);

  // D0: dtype sniff
  k_detect<<<1, 64, 0, stream>>>((const uint32_t*)x, flag);
  // T0: x -> Xt[m][w] bf16
  k_transpose<<<dim3(48, 64), 256, 0, stream>>>(x, Xt, flag);
  // C0: A -> Ab bf16; W/b -> Wb bf16
  k_cvtA<<<4608, 256, 0, stream>>>(A, Ab, flag);
  k_cvtW<<<1, 256, 0, stream>>>(W0, b0, W1, b1, Wb, flag);
  // K1: Gt[v][m] = Ab . Xt^T   (3072 x 4096, K=3072)
  k_gemm_nt<128><<<dim3(24, 32), 256, 0, stream>>>(Ab, Xt, Gt, 3072);
  // K2: H1[b*64+o][w] = GLU(W0 . Gt + b0)   (simple VALU)
  k_glu_simple<<<dim3(768, 64), 256, 0, stream>>>(Gt, Wb, Wb + 8192, H1, 3072);
  // K3: Gt2[v'][m] = Ab[1024+v'] . H1^T  (middle third only)
  k_gemm_nt<64><<<dim3(16, 32), 256, 0, stream>>>(Ab + (uint64_t)1024 * 3072, H1, Gt2, 3072);
  // K4: H2 = GLU(W1 . Gt2 + b1)   (simple VALU)
  k_glu_simple<<<dim3(256, 64), 256, 0, stream>>>(Gt2, Wb + 8320, Wb + 16512, H2, 1024);
  // K5: out = max(H1 crop, H2)   (simple scalar, fp32 out)
  k_max_simple<<<16384, 256, 0, stream>>>(H1, H2, out);
}

// Round 6
// 384.313 us; speedup vs baseline: 2.4508x; 2.4508x over previous
//
#include <hip/hip_runtime.h>
#include <hip/hip_bf16.h>
#include <stdint.h>

typedef __attribute__((ext_vector_type(8))) short s16x8;           // MFMA A/B frag: 8 bf16
typedef __attribute__((ext_vector_type(4))) float f32x4;           // MFMA C/D frag / fp32 vec4
typedef __attribute__((ext_vector_type(8))) unsigned short u16x8;  // 16B vector
typedef __attribute__((ext_vector_type(4))) unsigned short u16x4;  // 8B vector

__device__ __forceinline__ float bf2f(unsigned short u) {
  union { uint32_t u; float f; } v; v.u = ((uint32_t)u) << 16; return v.f;
}
__device__ __forceinline__ unsigned short f2bf(float f) {
  union { float f; uint32_t u; } v; v.f = f;
  uint32_t u = v.u;
  return (unsigned short)((u + 0x7fffu + ((u >> 16) & 1u)) >> 16);  // RNE
}
__device__ __forceinline__ void load_lds16(const void* g, void* l) {
  __builtin_amdgcn_global_load_lds(
      (const __attribute__((address_space(1))) void*)g,
      (__attribute__((address_space(3))) void*)l, 16, 0, 0);
}

// ---------------------------------------------------------------------------
// D0: dtype sniff (fp32 inputs -> flag=1). HW-validated r5.
// ---------------------------------------------------------------------------
__global__ void k_detect(const uint32_t* __restrict__ xw, int* __restrict__ flag) {
  int lane = threadIdx.x;  // 64 threads
  uint32_t u = xw[lane * 97 + 1];
  int e = (u >> 7) & 0xFF;
  unsigned long long m = __ballot(e > 150);
  if (lane == 0) *flag = (__popcll(m) > 6) ? 1 : 0;
}

// ---------------------------------------------------------------------------
// T0: x (3072 w x 4096 m) -> Xt (4096 m x 3072 w) bf16. HW-validated r5.
// ---------------------------------------------------------------------------
__global__ __launch_bounds__(256) void k_transpose(const void* __restrict__ xin,
                                                   unsigned short* __restrict__ xt,
                                                   const int* __restrict__ flag) {
  __shared__ __align__(16) unsigned short tile[64 * 65];
  const int t = threadIdx.x;
  const int w0 = blockIdx.x * 64;
  const int m0 = blockIdx.y * 64;
  if (*flag) {
    const float* xf = (const float*)xin;
#pragma unroll
    for (int rep = 0; rep < 4; ++rep) {
      int vi = t + rep * 256;
      int r = vi >> 4;
      int c4 = (vi & 15) * 4;
      f32x4 v = *(const f32x4*)(xf + (uint64_t)(w0 + r) * 4096 + m0 + c4);
#pragma unroll
      for (int u = 0; u < 4; ++u) tile[(c4 + u) * 65 + r] = f2bf(v[u]);
    }
  } else {
    const unsigned short* xb = (const unsigned short*)xin;
#pragma unroll
    for (int rep = 0; rep < 2; ++rep) {
      int vi = t + rep * 256;
      int r = vi >> 3;
      int c8 = (vi & 7) * 8;
      u16x8 v = *(const u16x8*)(xb + (uint64_t)(w0 + r) * 4096 + m0 + c8);
#pragma unroll
      for (int u = 0; u < 8; ++u) tile[(c8 + u) * 65 + r] = v[u];
    }
  }
  __syncthreads();
#pragma unroll
  for (int rep = 0; rep < 2; ++rep) {
    int vi = t + rep * 256;
    int r = vi >> 3;
    int c8 = (vi & 7) * 8;
    u16x8 v;
#pragma unroll
    for (int u = 0; u < 8; ++u) v[u] = tile[r * 65 + c8 + u];
    *(u16x8*)(xt + (uint64_t)(m0 + r) * 3072 + w0 + c8) = v;
  }
}

// ---------------------------------------------------------------------------
// A -> Ab bf16. HW-validated r5.
// ---------------------------------------------------------------------------
__global__ __launch_bounds__(256) void k_cvtA(const void* __restrict__ Ain,
                                              unsigned short* __restrict__ Ab,
                                              const int* __restrict__ flag) {
  uint64_t i = ((uint64_t)blockIdx.x * 256 + threadIdx.x) * 8;
  if (*flag) {
    const float* Af = (const float*)Ain;
    f32x4 a = *(const f32x4*)(Af + i);
    f32x4 b = *(const f32x4*)(Af + i + 4);
    u16x8 o;
#pragma unroll
    for (int u = 0; u < 4; ++u) { o[u] = f2bf(a[u]); o[u + 4] = f2bf(b[u]); }
    *(u16x8*)(Ab + i) = o;
  } else {
    *(u16x8*)(Ab + i) = *(const u16x8*)((const unsigned short*)Ain + i);
  }
}

// ---------------------------------------------------------------------------
// W0,b0,W1,b1 -> contiguous bf16 block wb[16640]. HW-validated r5.
// ---------------------------------------------------------------------------
__global__ __launch_bounds__(256) void k_cvtW(const void* __restrict__ W0,
                                              const void* __restrict__ b0,
                                              const void* __restrict__ W1,
                                              const void* __restrict__ b1,
                                              unsigned short* __restrict__ wb,
                                              const int* __restrict__ flag) {
  int fp = *flag;
  for (int i = threadIdx.x; i < 16640; i += 256) {
    const void* src; int off;
    if (i < 8192)        { src = W0; off = i; }
    else if (i < 8320)   { src = b0; off = i - 8192; }
    else if (i < 16512)  { src = W1; off = i - 8320; }
    else                 { src = b1; off = i - 16512; }
    wb[i] = fp ? f2bf(((const float*)src)[off]) : ((const unsigned short*)src)[off];
  }
}

// ---------------------------------------------------------------------------
// NT GEMM: C[v][m] = sum_k Am[v][k] * Bm[m][k]; C ld = 4096, bf16 out.
// m97-lineage K-loop + direct-store epilogue. HW-validated r5.
// ---------------------------------------------------------------------------
template <int BM>
__global__ __launch_bounds__(256) void k_gemm_nt(const unsigned short* __restrict__ Am,
                                                 const unsigned short* __restrict__ Bm,
                                                 unsigned short* __restrict__ Cm,
                                                 int K) {
  constexpr int IF = BM / 32;
  __shared__ __align__(16) unsigned short smem[BM * 64 + 128 * 64];
  unsigned short* At = smem;                     // [BM][64]
  unsigned short* Bt = smem + BM * 64;           // [128][64]

  const int t = threadIdx.x;
  const int lane = t & 63;
  const int wid = t >> 6;
  const int wV = wid >> 1;
  const int wM = wid & 1;
  const int v0 = blockIdx.x * BM;
  const int m0 = blockIdx.y * 128;

  f32x4 acc[IF][4] = {};

  const int arow = wid * (BM / 4) + (lane >> 3);
  const int brow = wid * 32 + (lane >> 3);
  const int scol = (lane & 7) * 8;
  const unsigned short* gA = Am + (uint64_t)(v0 + arow) * K + scol;
  const unsigned short* gB = Bm + (uint64_t)(m0 + brow) * K + scol;
  unsigned short* lA = At + wid * (BM / 4) * 64;
  unsigned short* lB = Bt + wid * 32 * 64;

  const int fr = lane & 15;
  const int fk = (lane >> 4) * 8;

  for (int kk = 0; kk < K; kk += 64) {
    __syncthreads();
#pragma unroll
    for (int q = 0; q < BM / 32; ++q)
      load_lds16(gA + (uint64_t)(q * 8) * K + kk, lA + q * 8 * 64);
#pragma unroll
    for (int q = 0; q < 4; ++q)
      load_lds16(gB + (uint64_t)(q * 8) * K + kk, lB + q * 8 * 64);
    __syncthreads();
#pragma unroll
    for (int ks = 0; ks < 64; ks += 32) {
      s16x8 af[IF], bf[4];
#pragma unroll
      for (int i = 0; i < IF; ++i)
        af[i] = *(const s16x8*)(At + (wV * (BM / 2) + i * 16 + fr) * 64 + ks + fk);
#pragma unroll
      for (int j = 0; j < 4; ++j)
        bf[j] = *(const s16x8*)(Bt + (wM * 64 + j * 16 + fr) * 64 + ks + fk);
#pragma unroll
      for (int i = 0; i < IF; ++i)
#pragma unroll
        for (int j = 0; j < 4; ++j)
          acc[i][j] = __builtin_amdgcn_mfma_f32_16x16x32_bf16(af[i], bf[j], acc[i][j], 0, 0, 0);
    }
  }

  const int rr = (lane >> 4) * 4;
#pragma unroll
  for (int i = 0; i < IF; ++i) {
    int vbase = v0 + wV * (BM / 2) + i * 16 + rr;
#pragma unroll
    for (int j = 0; j < 4; ++j) {
      int m = m0 + wM * 64 + j * 16 + fr;
#pragma unroll
      for (int r = 0; r < 4; ++r)
        Cm[(uint64_t)(vbase + r) * 4096 + m] = f2bf(acc[i][j][r]);
    }
  }
}

// ---------------------------------------------------------------------------
// MFMA GLU: 1x1 conv (64 -> 128 ch) + GLU. G: [V][4096] (cols m=b*64+c).
// H[(b*64+o)][v] (ld Vtot), o<64. Per block: 128 v x 1 b.
// Fragment conventions identical to k_gemm_nt (HW-validated r5):
//   A-dim(row) = (lane>>4)*4+reg, B-dim(col) = lane&15.
// ---------------------------------------------------------------------------
__global__ __launch_bounds__(256) void k_glu(const unsigned short* __restrict__ G,
                                             const unsigned short* __restrict__ W,
                                             const unsigned short* __restrict__ bias,
                                             unsigned short* __restrict__ H,
                                             int Vtot) {
  __shared__ __align__(16) unsigned short Gs[128 * 64];
  const int t = threadIdx.x;
  const int lane = t & 63;
  const int wid = t >> 6;
  const int v0 = blockIdx.x * 128;
  const int b = blockIdx.y;
  const int fr = lane & 15;
  const int fk = (lane >> 4) * 8;

  {
    const unsigned short* gG =
        G + (uint64_t)(v0 + wid * 32 + (lane >> 3)) * 4096 + b * 64 + (lane & 7) * 8;
    unsigned short* lG = Gs + wid * 32 * 64;
#pragma unroll
    for (int q = 0; q < 4; ++q)
      load_lds16(gG + (uint64_t)(q * 8) * 4096, lG + q * 8 * 64);
  }
  // W frags from global (L2-resident): B-operand rows o, k=c contiguous
  s16x8 wf[2][8];
#pragma unroll
  for (int ksi = 0; ksi < 2; ++ksi)
#pragma unroll
    for (int j = 0; j < 8; ++j)
      wf[ksi][j] = *(const s16x8*)(W + (j * 16 + fr) * 64 + ksi * 32 + fk);
  float bj[8];
#pragma unroll
  for (int j = 0; j < 8; ++j) bj[j] = bf2f(bias[j * 16 + fr]);

  __syncthreads();
  f32x4 acc[2][8] = {};
#pragma unroll
  for (int mi = 0; mi < 2; ++mi)
#pragma unroll
    for (int ksi = 0; ksi < 2; ++ksi) {
      s16x8 af = *(const s16x8*)(Gs + (wid * 32 + mi * 16 + fr) * 64 + ksi * 32 + fk);
#pragma unroll
      for (int j = 0; j < 8; ++j)
        acc[mi][j] = __builtin_amdgcn_mfma_f32_16x16x32_bf16(af, wf[ksi][j], acc[mi][j], 0, 0, 0);
    }

  // GLU: h[o] = y[o] * sigmoid(y[o+64]); frag j (o=j*16+fr) pairs with j+4
#pragma unroll
  for (int mi = 0; mi < 2; ++mi) {
    int v = v0 + wid * 32 + mi * 16 + (lane >> 4) * 4;
#pragma unroll
    for (int j = 0; j < 4; ++j) {
      u16x4 pk;
#pragma unroll
      for (int r = 0; r < 4; ++r) {
        float lhs = acc[mi][j][r] + bj[j];
        float rhs = acc[mi][j + 4][r] + bj[j + 4];
        float sg = 1.0f / (1.0f + __expf(-rhs));
        pk[r] = f2bf(lhs * sg);
      }
      int o = j * 16 + fr;
      *(u16x4*)(H + (uint64_t)(b * 64 + o) * Vtot + v) = pk;
    }
  }
}

// ---------------------------------------------------------------------------
// out[n][b][j] = max(H1[b*64+j][1024+n], H2[b*64+j][n]); fp32 out,
// (j,n)-transpose via LDS, vectorized both sides.
// ---------------------------------------------------------------------------
__global__ __launch_bounds__(256) void k_maxout(const unsigned short* __restrict__ H1,
                                                const unsigned short* __restrict__ H2,
                                                float* __restrict__ out) {
  __shared__ __align__(16) float tile[64 * 65];  // [j][n]
  const int t = threadIdx.x;
  const int b = blockIdx.y;
  const int n0 = blockIdx.x * 64;
  {
    int j = t >> 2, p = t & 3;
    const unsigned short* h1p = H1 + (uint64_t)(b * 64 + j) * 3072 + 1024 + n0 + p * 16;
    const unsigned short* h2p = H2 + (uint64_t)(b * 64 + j) * 1024 + n0 + p * 16;
    u16x8 a0 = *(const u16x8*)(h1p);
    u16x8 a1 = *(const u16x8*)(h1p + 8);
    u16x8 c0 = *(const u16x8*)(h2p);
    u16x8 c1 = *(const u16x8*)(h2p + 8);
#pragma unroll
    for (int u = 0; u < 8; ++u) {
      tile[j * 65 + p * 16 + u] = fmaxf(bf2f(a0[u]), bf2f(c0[u]));
      tile[j * 65 + p * 16 + 8 + u] = fmaxf(bf2f(a1[u]), bf2f(c1[u]));
    }
  }
  __syncthreads();
  {
    int n = t >> 2, jb = (t & 3) * 16;
    float* op = out + (uint64_t)(n0 + n) * 4096 + b * 64 + jb;
#pragma unroll
    for (int q = 0; q < 4; ++q) {
      f32x4 o;
#pragma unroll
      for (int u = 0; u < 4; ++u) o[u] = tile[(jb + q * 4 + u) * 65 + n];
      *(f32x4*)(op + q * 4) = o;
    }
  }
}

// ---------------------------------------------------------------------------
extern "C" void kernel_launch(void* const* d_in, const int* in_sizes, int n_in,
                              void* d_out, int out_size, void* d_ws, size_t ws_size,
                              hipStream_t stream) {
  (void)in_sizes; (void)n_in; (void)out_size; (void)ws_size;
  const void* x  = d_in[0];  // [3072][64][64]
  const void* A  = d_in[1];  // [3072][3072]
  const void* W0 = d_in[2];  // [128][64]
  const void* b0 = d_in[3];  // [128]
  const void* W1 = d_in[4];  // [128][64]
  const void* b1 = d_in[5];  // [128]
  float* out = (float*)d_out;  // [1024][64][64] fp32

  char* ws = (char*)d_ws;
  unsigned short* Xt  = (unsigned short*)(ws + 0);         // 25165824 B
  unsigned short* Ab  = (unsigned short*)(ws + 25165824);  // 18874368 B
  unsigned short* Wb  = (unsigned short*)(ws + 44040192);  // 33280 B
  unsigned short* Gt  = (unsigned short*)(ws + 44105728);  // 25165824 B
  unsigned short* H1  = (unsigned short*)(ws + 0);         // overlays Xt (dead after K1)
  unsigned short* Gt2 = (unsigned short*)(ws + 44105728);  // overlays Gt (dead after K2)
  unsigned short* H2  = (unsigned short*)(ws + 52494336);  // 8388608 B
  int* flag = (int*)(ws + 69271552);

  // D0: dtype sniff
  k_detect<<<1, 64, 0, stream>>>((const uint32_t*)x, flag);
  // T0: x -> Xt[m][w] bf16
  k_transpose<<<dim3(48, 64), 256, 0, stream>>>(x, Xt, flag);
  // C0: A -> Ab bf16; W/b -> Wb bf16
  k_cvtA<<<4608, 256, 0, stream>>>(A, Ab, flag);
  k_cvtW<<<1, 256, 0, stream>>>(W0, b0, W1, b1, Wb, flag);
  // K1: Gt[v][m] = Ab . Xt^T   (3072 x 4096, K=3072)
  k_gemm_nt<128><<<dim3(24, 32), 256, 0, stream>>>(Ab, Xt, Gt, 3072);
  // K2: H1[b*64+o][w] = GLU(W0 . Gt + b0)   (MFMA)
  k_glu<<<dim3(24, 64), 256, 0, stream>>>(Gt, Wb, Wb + 8192, H1, 3072);
  // K3: Gt2[v'][m] = Ab[1024+v'] . H1^T  (middle third only)
  k_gemm_nt<64><<<dim3(16, 32), 256, 0, stream>>>(Ab + (uint64_t)1024 * 3072, H1, Gt2, 3072);
  // K4: H2 = GLU(W1 . Gt2 + b1)   (MFMA)
  k_glu<<<dim3(8, 64), 256, 0, stream>>>(Gt2, Wb + 8320, Wb + 16512, H2, 1024);
  // K5: out = max(H1 crop, H2)   (fp32 out, LDS transpose)
  k_maxout<<<dim3(16, 64), 256, 0, stream>>>(H1, H2, out);
}

// Round 7
// 378.315 us; speedup vs baseline: 2.4896x; 1.0159x over previous
//
#include <hip/hip_runtime.h>
#include <hip/hip_bf16.h>
#include <stdint.h>

typedef __attribute__((ext_vector_type(8))) short s16x8;           // MFMA A/B frag: 8 bf16
typedef __attribute__((ext_vector_type(4))) float f32x4;           // MFMA C/D frag / fp32 vec4
typedef __attribute__((ext_vector_type(8))) unsigned short u16x8;  // 16B vector
typedef __attribute__((ext_vector_type(4))) unsigned short u16x4;  // 8B vector

__device__ __forceinline__ float bf2f(unsigned short u) {
  union { uint32_t u; float f; } v; v.u = ((uint32_t)u) << 16; return v.f;
}
__device__ __forceinline__ unsigned short f2bf(float f) {
  union { float f; uint32_t u; } v; v.f = f;
  uint32_t u = v.u;
  return (unsigned short)((u + 0x7fffu + ((u >> 16) & 1u)) >> 16);  // RNE
}
__device__ __forceinline__ void load_lds16(const void* g, void* l) {
  __builtin_amdgcn_global_load_lds(
      (const __attribute__((address_space(1))) void*)g,
      (__attribute__((address_space(3))) void*)l, 16, 0, 0);
}

// ---------------------------------------------------------------------------
// D0: dtype sniff (fp32 inputs -> flag=1). HW-validated r5/r6.
// ---------------------------------------------------------------------------
__global__ void k_detect(const uint32_t* __restrict__ xw, int* __restrict__ flag) {
  int lane = threadIdx.x;  // 64 threads
  uint32_t u = xw[lane * 97 + 1];
  int e = (u >> 7) & 0xFF;
  unsigned long long m = __ballot(e > 150);
  if (lane == 0) *flag = (__popcll(m) > 6) ? 1 : 0;
}

// ---------------------------------------------------------------------------
// T0: x (3072 w x 4096 m) -> Xt (4096 m x 3072 w) bf16. HW-validated r5/r6.
// ---------------------------------------------------------------------------
__global__ __launch_bounds__(256) void k_transpose(const void* __restrict__ xin,
                                                   unsigned short* __restrict__ xt,
                                                   const int* __restrict__ flag) {
  __shared__ __align__(16) unsigned short tile[64 * 65];
  const int t = threadIdx.x;
  const int w0 = blockIdx.x * 64;
  const int m0 = blockIdx.y * 64;
  if (*flag) {
    const float* xf = (const float*)xin;
#pragma unroll
    for (int rep = 0; rep < 4; ++rep) {
      int vi = t + rep * 256;
      int r = vi >> 4;
      int c4 = (vi & 15) * 4;
      f32x4 v = *(const f32x4*)(xf + (uint64_t)(w0 + r) * 4096 + m0 + c4);
#pragma unroll
      for (int u = 0; u < 4; ++u) tile[(c4 + u) * 65 + r] = f2bf(v[u]);
    }
  } else {
    const unsigned short* xb = (const unsigned short*)xin;
#pragma unroll
    for (int rep = 0; rep < 2; ++rep) {
      int vi = t + rep * 256;
      int r = vi >> 3;
      int c8 = (vi & 7) * 8;
      u16x8 v = *(const u16x8*)(xb + (uint64_t)(w0 + r) * 4096 + m0 + c8);
#pragma unroll
      for (int u = 0; u < 8; ++u) tile[(c8 + u) * 65 + r] = v[u];
    }
  }
  __syncthreads();
#pragma unroll
  for (int rep = 0; rep < 2; ++rep) {
    int vi = t + rep * 256;
    int r = vi >> 3;
    int c8 = (vi & 7) * 8;
    u16x8 v;
#pragma unroll
    for (int u = 0; u < 8; ++u) v[u] = tile[r * 65 + c8 + u];
    *(u16x8*)(xt + (uint64_t)(m0 + r) * 3072 + w0 + c8) = v;
  }
}

// ---------------------------------------------------------------------------
// A -> Ab bf16. HW-validated r5/r6.
// ---------------------------------------------------------------------------
__global__ __launch_bounds__(256) void k_cvtA(const void* __restrict__ Ain,
                                              unsigned short* __restrict__ Ab,
                                              const int* __restrict__ flag) {
  uint64_t i = ((uint64_t)blockIdx.x * 256 + threadIdx.x) * 8;
  if (*flag) {
    const float* Af = (const float*)Ain;
    f32x4 a = *(const f32x4*)(Af + i);
    f32x4 b = *(const f32x4*)(Af + i + 4);
    u16x8 o;
#pragma unroll
    for (int u = 0; u < 4; ++u) { o[u] = f2bf(a[u]); o[u + 4] = f2bf(b[u]); }
    *(u16x8*)(Ab + i) = o;
  } else {
    *(u16x8*)(Ab + i) = *(const u16x8*)((const unsigned short*)Ain + i);
  }
}

// ---------------------------------------------------------------------------
// W0,b0,W1,b1 -> contiguous bf16 block wb[16640]. HW-validated r5/r6.
// ---------------------------------------------------------------------------
__global__ __launch_bounds__(256) void k_cvtW(const void* __restrict__ W0,
                                              const void* __restrict__ b0,
                                              const void* __restrict__ W1,
                                              const void* __restrict__ b1,
                                              unsigned short* __restrict__ wb,
                                              const int* __restrict__ flag) {
  int fp = *flag;
  for (int i = threadIdx.x; i < 16640; i += 256) {
    const void* src; int off;
    if (i < 8192)        { src = W0; off = i; }
    else if (i < 8320)   { src = b0; off = i - 8192; }
    else if (i < 16512)  { src = W1; off = i - 8320; }
    else                 { src = b1; off = i - 16512; }
    wb[i] = fp ? f2bf(((const float*)src)[off]) : ((const unsigned short*)src)[off];
  }
}

// ---------------------------------------------------------------------------
// Fused NT GEMM + 1x1 conv + GLU.
//   G[v][m] = sum_k Am[v][k] * Bm[m][k]      (m = b*64 + c, 2 b's per block)
//   y[b][o][v] = sum_c W[o][c] * G[v][b*64+c] + bias[o]     (o < 128)
//   H[(bg*64+o)][v] = y[o] * sigmoid(y[o+64])               (o < 64)
// Main K-loop + direct conv: HW-validated structures (r5/r6 k_gemm_nt + k_glu);
// new glue: acc -> LDS G-tile [BM][136] bf16, conv A-frags read from LDS.
// ---------------------------------------------------------------------------
template <int BM>
__global__ __launch_bounds__(256) void k_gemm_glu(const unsigned short* __restrict__ Am,
                                                  const unsigned short* __restrict__ Bm,
                                                  const unsigned short* __restrict__ W,
                                                  const unsigned short* __restrict__ bias,
                                                  unsigned short* __restrict__ H,
                                                  int K, int Vtot) {
  constexpr int IF = BM / 32;                    // main-loop v-frags per wave
  constexpr int VPW = BM / 64;                   // epilogue v-frags per wave
  constexpr int STAGE = BM * 64 + 128 * 64;      // A tile + B tile (ushorts)
  constexpr int GTILE = BM * 136;                // bf16 G tile, padded ld (272B rows, 16B-aligned)
  constexpr int SME = STAGE > GTILE ? STAGE : GTILE;
  __shared__ __align__(16) unsigned short smem[SME];
  unsigned short* At = smem;                     // [BM][64]
  unsigned short* Bt = smem + BM * 64;           // [128][64]

  const int t = threadIdx.x;
  const int lane = t & 63;
  const int wid = t >> 6;
  const int wV = wid >> 1;
  const int wM = wid & 1;
  const int v0 = blockIdx.x * BM;
  const int m0 = blockIdx.y * 128;

  f32x4 acc[IF][4] = {};

  const int arow = wid * (BM / 4) + (lane >> 3);
  const int brow = wid * 32 + (lane >> 3);
  const int scol = (lane & 7) * 8;
  const unsigned short* gA = Am + (uint64_t)(v0 + arow) * K + scol;
  const unsigned short* gB = Bm + (uint64_t)(m0 + brow) * K + scol;
  unsigned short* lA = At + wid * (BM / 4) * 64;
  unsigned short* lB = Bt + wid * 32 * 64;

  const int fr = lane & 15;
  const int fk = (lane >> 4) * 8;

  for (int kk = 0; kk < K; kk += 64) {
    __syncthreads();
#pragma unroll
    for (int q = 0; q < BM / 32; ++q)
      load_lds16(gA + (uint64_t)(q * 8) * K + kk, lA + q * 8 * 64);
#pragma unroll
    for (int q = 0; q < 4; ++q)
      load_lds16(gB + (uint64_t)(q * 8) * K + kk, lB + q * 8 * 64);
    __syncthreads();
#pragma unroll
    for (int ks = 0; ks < 64; ks += 32) {
      s16x8 af[IF], bf[4];
#pragma unroll
      for (int i = 0; i < IF; ++i)
        af[i] = *(const s16x8*)(At + (wV * (BM / 2) + i * 16 + fr) * 64 + ks + fk);
#pragma unroll
      for (int j = 0; j < 4; ++j)
        bf[j] = *(const s16x8*)(Bt + (wM * 64 + j * 16 + fr) * 64 + ks + fk);
#pragma unroll
      for (int i = 0; i < IF; ++i)
#pragma unroll
        for (int j = 0; j < 4; ++j)
          acc[i][j] = __builtin_amdgcn_mfma_f32_16x16x32_bf16(af[i], bf[j], acc[i][j], 0, 0, 0);
    }
  }

  // ---- epilogue: G-tile to LDS, then conv+GLU (k_glu-validated structure) ----
  __syncthreads();  // all waves done reading At/Bt before overwrite
  {
    const int rr = (lane >> 4) * 4;
#pragma unroll
    for (int i = 0; i < IF; ++i)
#pragma unroll
      for (int j = 0; j < 4; ++j) {
        int col = wM * 64 + j * 16 + fr;
#pragma unroll
        for (int r = 0; r < 4; ++r) {
          int row = wV * (BM / 2) + i * 16 + rr + r;
          smem[row * 136 + col] = f2bf(acc[i][j][r]);
        }
      }
  }
  __syncthreads();

  // W frags (B-operand, rows o, k=c contiguous) from global (L2-resident)
  s16x8 wf[2][8];
#pragma unroll
  for (int ksi = 0; ksi < 2; ++ksi)
#pragma unroll
    for (int j = 0; j < 8; ++j)
      wf[ksi][j] = *(const s16x8*)(W + (j * 16 + fr) * 64 + ksi * 32 + fk);
  float bj[8];
#pragma unroll
  for (int j = 0; j < 8; ++j) bj[j] = bf2f(bias[j * 16 + fr]);

#pragma unroll
  for (int b = 0; b < 2; ++b) {
    f32x4 acc2[VPW][8] = {};
#pragma unroll
    for (int vv = 0; vv < VPW; ++vv)
#pragma unroll
      for (int ksi = 0; ksi < 2; ++ksi) {
        s16x8 af = *(const s16x8*)(smem + ((wid * VPW + vv) * 16 + fr) * 136 +
                                   b * 64 + ksi * 32 + fk);
#pragma unroll
        for (int j = 0; j < 8; ++j)
          acc2[vv][j] = __builtin_amdgcn_mfma_f32_16x16x32_bf16(af, wf[ksi][j], acc2[vv][j], 0, 0, 0);
      }
    // GLU: h[o] = y[o]*sigmoid(y[o+64]); frag j (o=j*16+fr) pairs with j+4
#pragma unroll
    for (int vv = 0; vv < VPW; ++vv) {
      int v = v0 + (wid * VPW + vv) * 16 + (lane >> 4) * 4;
#pragma unroll
      for (int j = 0; j < 4; ++j) {
        u16x4 pk;
#pragma unroll
        for (int r = 0; r < 4; ++r) {
          float lhs = acc2[vv][j][r] + bj[j];
          float rhs = acc2[vv][j + 4][r] + bj[j + 4];
          float sg = 1.0f / (1.0f + __expf(-rhs));
          pk[r] = f2bf(lhs * sg);
        }
        int o = j * 16 + fr;
        *(u16x4*)(H + (uint64_t)(m0 + b * 64 + o) * Vtot + v) = pk;
      }
    }
  }
}

// ---------------------------------------------------------------------------
// out[n][b][j] = max(H1[b*64+j][1024+n], H2[b*64+j][n]); fp32 out,
// (j,n)-transpose via LDS. HW-validated r6.
// ---------------------------------------------------------------------------
__global__ __launch_bounds__(256) void k_maxout(const unsigned short* __restrict__ H1,
                                                const unsigned short* __restrict__ H2,
                                                float* __restrict__ out) {
  __shared__ __align__(16) float tile[64 * 65];  // [j][n]
  const int t = threadIdx.x;
  const int b = blockIdx.y;
  const int n0 = blockIdx.x * 64;
  {
    int j = t >> 2, p = t & 3;
    const unsigned short* h1p = H1 + (uint64_t)(b * 64 + j) * 3072 + 1024 + n0 + p * 16;
    const unsigned short* h2p = H2 + (uint64_t)(b * 64 + j) * 1024 + n0 + p * 16;
    u16x8 a0 = *(const u16x8*)(h1p);
    u16x8 a1 = *(const u16x8*)(h1p + 8);
    u16x8 c0 = *(const u16x8*)(h2p);
    u16x8 c1 = *(const u16x8*)(h2p + 8);
#pragma unroll
    for (int u = 0; u < 8; ++u) {
      tile[j * 65 + p * 16 + u] = fmaxf(bf2f(a0[u]), bf2f(c0[u]));
      tile[j * 65 + p * 16 + 8 + u] = fmaxf(bf2f(a1[u]), bf2f(c1[u]));
    }
  }
  __syncthreads();
  {
    int n = t >> 2, jb = (t & 3) * 16;
    float* op = out + (uint64_t)(n0 + n) * 4096 + b * 64 + jb;
#pragma unroll
    for (int q = 0; q < 4; ++q) {
      f32x4 o;
#pragma unroll
      for (int u = 0; u < 4; ++u) o[u] = tile[(jb + q * 4 + u) * 65 + n];
      *(f32x4*)(op + q * 4) = o;
    }
  }
}

// ---------------------------------------------------------------------------
extern "C" void kernel_launch(void* const* d_in, const int* in_sizes, int n_in,
                              void* d_out, int out_size, void* d_ws, size_t ws_size,
                              hipStream_t stream) {
  (void)in_sizes; (void)n_in; (void)out_size; (void)ws_size;
  const void* x  = d_in[0];  // [3072][64][64]
  const void* A  = d_in[1];  // [3072][3072]
  const void* W0 = d_in[2];  // [128][64]
  const void* b0 = d_in[3];  // [128]
  const void* W1 = d_in[4];  // [128][64]
  const void* b1 = d_in[5];  // [128]
  float* out = (float*)d_out;  // [1024][64][64] fp32

  char* ws = (char*)d_ws;
  // [0, 25.2M): Xt (dead after K1f) -> H2 overlay (written by K3f)
  unsigned short* Xt  = (unsigned short*)(ws + 0);         // 25165824 B
  unsigned short* H2  = (unsigned short*)(ws + 0);         // 8388608 B (overlay)
  unsigned short* Ab  = (unsigned short*)(ws + 25165824);  // 18874368 B
  unsigned short* Wb  = (unsigned short*)(ws + 44040192);  // 33280 B
  unsigned short* H1  = (unsigned short*)(ws + 44105728);  // 25165824 B -> end 69271552
  int* flag = (int*)(ws + 69271552);

  // D0: dtype sniff
  k_detect<<<1, 64, 0, stream>>>((const uint32_t*)x, flag);
  // T0: x -> Xt[m][w] bf16
  k_transpose<<<dim3(48, 64), 256, 0, stream>>>(x, Xt, flag);
  // C0: A -> Ab bf16; W/b -> Wb bf16
  k_cvtA<<<4608, 256, 0, stream>>>(A, Ab, flag);
  k_cvtW<<<1, 256, 0, stream>>>(W0, b0, W1, b1, Wb, flag);
  // K1f: H1[(b*64+o)][w] = GLU(W0 . (Ab . Xt^T) + b0)   (fused, v covers 3072)
  k_gemm_glu<128><<<dim3(24, 32), 256, 0, stream>>>(Ab, Xt, Wb, Wb + 8192, H1, 3072, 3072);
  // K3f: H2[(b*64+o)][v'] = GLU(W1 . (Ab[1024+v'] . H1^T) + b1)  (middle third)
  k_gemm_glu<64><<<dim3(16, 32), 256, 0, stream>>>(Ab + (uint64_t)1024 * 3072, H1, Wb + 8320,
                                                    Wb + 16512, H2, 3072, 1024);
  // K5: out = max(H1 crop, H2)
  k_maxout<<<dim3(16, 64), 256, 0, stream>>>(H1, H2, out);
}

// Round 9
// 318.578 us; speedup vs baseline: 2.9565x; 1.1875x over previous
//
#include <hip/hip_runtime.h>
#include <hip/hip_bf16.h>
#include <stdint.h>

typedef __attribute__((ext_vector_type(8))) short s16x8;           // MFMA A/B frag: 8 bf16
typedef __attribute__((ext_vector_type(4))) float f32x4;           // MFMA C/D frag / fp32 vec4
typedef __attribute__((ext_vector_type(8))) unsigned short u16x8;  // 16B vector
typedef __attribute__((ext_vector_type(4))) unsigned short u16x4;  // 8B vector

__device__ __forceinline__ float bf2f(unsigned short u) {
  union { uint32_t u; float f; } v; v.u = ((uint32_t)u) << 16; return v.f;
}
__device__ __forceinline__ unsigned short f2bf(float f) {
  union { float f; uint32_t u; } v; v.f = f;
  uint32_t u = v.u;
  return (unsigned short)((u + 0x7fffu + ((u >> 16) & 1u)) >> 16);  // RNE
}
__device__ __forceinline__ void load_lds16(const void* g, void* l) {
  __builtin_amdgcn_global_load_lds(
      (const __attribute__((address_space(1))) void*)g,
      (__attribute__((address_space(3))) void*)l, 16, 0, 0);
}

// PACKED LAYOUT: matrix [R][Kd] -> tiles 64r x 64k. Tile (rt,kt) at ushort
// offset (rt*(Kd/64)+kt)*4096; within tile: plane kb (k=kb*8+e) at kb*512,
// row r at r*8, elem e. Plane = 1 KB = one global_load_lds wave-instruction.
// NOTE: global_load_lds needs a PER-LANE global address (lane*16B) and a
// wave-uniform LDS base (r8 bug: wave-uniform global addr -> replicated junk).

// ---------------------------------------------------------------------------
// D0: dtype sniff (fp32 inputs -> flag=1). HW-validated r5-r7.
// ---------------------------------------------------------------------------
__global__ void k_detect(const uint32_t* __restrict__ xw, int* __restrict__ flag) {
  int lane = threadIdx.x;  // 64 threads
  uint32_t u = xw[lane * 97 + 1];
  int e = (u >> 7) & 0xFF;
  unsigned long long m = __ballot(e > 150);
  if (lane == 0) *flag = (__popcll(m) > 6) ? 1 : 0;
}

// ---------------------------------------------------------------------------
// T0: x (3072 w x 4096 m) -> Xtp packed (rows m, k=w). One packed tile/block.
// ---------------------------------------------------------------------------
__global__ __launch_bounds__(256) void k_transpose(const void* __restrict__ xin,
                                                   unsigned short* __restrict__ xtp,
                                                   const int* __restrict__ flag) {
  __shared__ __align__(16) unsigned short tile[64 * 65];  // [m-local][w-local]
  const int t = threadIdx.x;
  const int w0 = blockIdx.x * 64;
  const int m0 = blockIdx.y * 64;
  if (*flag) {
    const float* xf = (const float*)xin;
#pragma unroll
    for (int rep = 0; rep < 4; ++rep) {
      int vi = t + rep * 256;
      int r = vi >> 4;                // w-local
      int c4 = (vi & 15) * 4;        // m-local
      f32x4 v = *(const f32x4*)(xf + (uint64_t)(w0 + r) * 4096 + m0 + c4);
#pragma unroll
      for (int u = 0; u < 4; ++u) tile[(c4 + u) * 65 + r] = f2bf(v[u]);
    }
  } else {
    const unsigned short* xb = (const unsigned short*)xin;
#pragma unroll
    for (int rep = 0; rep < 2; ++rep) {
      int vi = t + rep * 256;
      int r = vi >> 3;
      int c8 = (vi & 7) * 8;
      u16x8 v = *(const u16x8*)(xb + (uint64_t)(w0 + r) * 4096 + m0 + c8);
#pragma unroll
      for (int u = 0; u < 8; ++u) tile[(c8 + u) * 65 + r] = v[u];
    }
  }
  __syncthreads();
  unsigned short* dst = xtp + ((uint64_t)(m0 >> 6) * 48 + (w0 >> 6)) * 4096;
#pragma unroll
  for (int rep = 0; rep < 2; ++rep) {
    int vi = t + rep * 256;           // [0,512)
    int kb = vi >> 6, r = vi & 63;
    u16x8 v;
#pragma unroll
    for (int u = 0; u < 8; ++u) v[u] = tile[r * 65 + kb * 8 + u];
    *(u16x8*)(dst + kb * 512 + r * 8) = v;
  }
}

// ---------------------------------------------------------------------------
// A (3072x3072) -> Abp packed. One tile/block, LDS bounce for coalescing.
// ---------------------------------------------------------------------------
__global__ __launch_bounds__(256) void k_packA(const void* __restrict__ Ain,
                                               unsigned short* __restrict__ Abp,
                                               const int* __restrict__ flag) {
  __shared__ __align__(16) unsigned short tl[8 * 520];  // planes padded +8
  const int t = threadIdx.x;
  const int kt = blockIdx.x, rt = blockIdx.y;
  if (*flag) {
    const float* Af = (const float*)Ain;
#pragma unroll
    for (int rep = 0; rep < 4; ++rep) {
      int vi = t + rep * 256;
      int r = vi >> 4;
      int c4 = (vi & 15) * 4;
      f32x4 v = *(const f32x4*)(Af + (uint64_t)(rt * 64 + r) * 3072 + kt * 64 + c4);
      int kb = c4 >> 3, e = c4 & 7;
#pragma unroll
      for (int u = 0; u < 4; ++u) tl[kb * 520 + r * 8 + e + u] = f2bf(v[u]);
    }
  } else {
    const unsigned short* Ab16 = (const unsigned short*)Ain;
#pragma unroll
    for (int rep = 0; rep < 2; ++rep) {
      int vi = t + rep * 256;
      int r = vi >> 3;
      int c8 = (vi & 7) * 8;
      u16x8 v = *(const u16x8*)(Ab16 + (uint64_t)(rt * 64 + r) * 3072 + kt * 64 + c8);
#pragma unroll
      for (int u = 0; u < 8; ++u) tl[(c8 >> 3) * 520 + r * 8 + u] = v[u];
    }
  }
  __syncthreads();
  unsigned short* dst = Abp + ((uint64_t)rt * 48 + kt) * 4096;
#pragma unroll
  for (int rep = 0; rep < 2; ++rep) {
    int vi = t + rep * 256;
    int kb = vi >> 6, r = vi & 63;
    u16x8 v;
#pragma unroll
    for (int u = 0; u < 8; ++u) v[u] = tl[kb * 520 + r * 8 + u];
    *(u16x8*)(dst + kb * 512 + r * 8) = v;
  }
}

// ---------------------------------------------------------------------------
// W0,b0,W1,b1 -> contiguous bf16 block wb[16640]. HW-validated r5-r7.
// ---------------------------------------------------------------------------
__global__ __launch_bounds__(256) void k_cvtW(const void* __restrict__ W0,
                                              const void* __restrict__ b0,
                                              const void* __restrict__ W1,
                                              const void* __restrict__ b1,
                                              unsigned short* __restrict__ wb,
                                              const int* __restrict__ flag) {
  int fp = *flag;
  for (int i = threadIdx.x; i < 16640; i += 256) {
    const void* src; int off;
    if (i < 8192)        { src = W0; off = i; }
    else if (i < 8320)   { src = b0; off = i - 8192; }
    else if (i < 16512)  { src = W1; off = i - 8320; }
    else                 { src = b1; off = i - 16512; }
    wb[i] = fp ? f2bf(((const float*)src)[off]) : ((const unsigned short*)src)[off];
  }
}

// ---------------------------------------------------------------------------
// Fused NT GEMM + 1x1 conv + GLU, packed operands (A, B, H all packed).
// K-loop lane semantics identical to r7; conflict-free LDS addressing.
// ---------------------------------------------------------------------------
template <int BM>
__global__ __launch_bounds__(256) void k_gemm_glu(const unsigned short* __restrict__ Am,
                                                  const unsigned short* __restrict__ Bm,
                                                  const unsigned short* __restrict__ W,
                                                  const unsigned short* __restrict__ bias,
                                                  unsigned short* __restrict__ H,
                                                  int K, int Vtot) {
  constexpr int IF = BM / 32;
  constexpr int VPW = BM / 64;
  constexpr int NTA = BM / 64;                   // A tiles per block
  constexpr int NT = NTA + 2;                    // total staged tiles
  constexpr int STAGE = NT * 4096;
  constexpr int GTILE = BM * 136;
  constexpr int SME = STAGE > GTILE ? STAGE : GTILE;
  __shared__ __align__(16) unsigned short smem[SME];

  const int t = threadIdx.x;
  const int lane = t & 63;
  const int wid = t >> 6;
  const int wV = wid >> 1;
  const int wM = wid & 1;
  const int v0 = blockIdx.x * BM;
  const int m0 = blockIdx.y * 128;
  const int Kt = K >> 6;

  f32x4 acc[IF][4] = {};

  // staging: wave wid owns tile wid; PER-LANE global addr (+lane*16B)
  const unsigned short* tbase = nullptr;
  if (wid < NT) {
    tbase = (wid < NTA)
                ? Am + ((uint64_t)((v0 >> 6) + wid) * Kt) * 4096
                : Bm + ((uint64_t)((m0 >> 6) + (wid - NTA)) * Kt) * 4096;
    tbase += lane * 8;  // lane's 16-byte chunk (r8 bugfix)
  }
  unsigned short* lbase = smem + wid * 4096;

  const int fr = lane & 15;
  const int q4 = lane >> 4;

  for (int kt = 0; kt < Kt; ++kt) {
    __syncthreads();
    if (wid < NT) {
      const unsigned short* src = tbase + (uint64_t)kt * 4096;
#pragma unroll
      for (int q = 0; q < 8; ++q)
        load_lds16(src + q * 512, lbase + q * 512);
    }
    __syncthreads();
#pragma unroll
    for (int ks = 0; ks < 64; ks += 32) {
      const int kb = (ks >> 3) + q4;
      s16x8 af[IF], bf[4];
#pragma unroll
      for (int i = 0; i < IF; ++i) {
        int row = wV * (BM / 2) + i * 16 + fr;
        af[i] = *(const s16x8*)(smem + (row >> 6) * 4096 + kb * 512 + (row & 63) * 8);
      }
#pragma unroll
      for (int j = 0; j < 4; ++j) {
        int row = wM * 64 + j * 16 + fr;
        bf[j] = *(const s16x8*)(smem + (NTA + (row >> 6)) * 4096 + kb * 512 + (row & 63) * 8);
      }
#pragma unroll
      for (int i = 0; i < IF; ++i)
#pragma unroll
        for (int j = 0; j < 4; ++j)
          acc[i][j] = __builtin_amdgcn_mfma_f32_16x16x32_bf16(af[i], bf[j], acc[i][j], 0, 0, 0);
    }
  }

  // ---- epilogue: G-tile to LDS, conv+GLU (r6/r7-validated structure) ----
  __syncthreads();
  {
    const int rr = q4 * 4;
#pragma unroll
    for (int i = 0; i < IF; ++i)
#pragma unroll
      for (int j = 0; j < 4; ++j) {
        int col = wM * 64 + j * 16 + fr;
#pragma unroll
        for (int r = 0; r < 4; ++r) {
          int row = wV * (BM / 2) + i * 16 + rr + r;
          smem[row * 136 + col] = f2bf(acc[i][j][r]);
        }
      }
  }
  __syncthreads();

  s16x8 wf[2][8];
#pragma unroll
  for (int ksi = 0; ksi < 2; ++ksi)
#pragma unroll
    for (int j = 0; j < 8; ++j)
      wf[ksi][j] = *(const s16x8*)(W + (j * 16 + fr) * 64 + ksi * 32 + q4 * 8);
  float bj[8];
#pragma unroll
  for (int j = 0; j < 8; ++j) bj[j] = bf2f(bias[j * 16 + fr]);

  const int Vt = Vtot >> 6;
#pragma unroll
  for (int b = 0; b < 2; ++b) {
    f32x4 acc2[VPW][8] = {};
#pragma unroll
    for (int vv = 0; vv < VPW; ++vv)
#pragma unroll
      for (int ksi = 0; ksi < 2; ++ksi) {
        s16x8 af = *(const s16x8*)(smem + ((wid * VPW + vv) * 16 + fr) * 136 +
                                   b * 64 + ksi * 32 + q4 * 8);
#pragma unroll
        for (int j = 0; j < 8; ++j)
          acc2[vv][j] = __builtin_amdgcn_mfma_f32_16x16x32_bf16(af, wf[ksi][j], acc2[vv][j], 0, 0, 0);
      }
#pragma unroll
    for (int vv = 0; vv < VPW; ++vv) {
      int v = v0 + (wid * VPW + vv) * 16 + q4 * 4;
#pragma unroll
      for (int j = 0; j < 4; ++j) {
        u16x4 pk;
#pragma unroll
        for (int r = 0; r < 4; ++r) {
          float lhs = acc2[vv][j][r] + bj[j];
          float rhs = acc2[vv][j + 4][r] + bj[j + 4];
          float sg = 1.0f / (1.0f + __expf(-rhs));
          pk[r] = f2bf(lhs * sg);
        }
        int o = j * 16 + fr;
        int hrow = m0 + b * 64 + o;
        *(u16x4*)(H + ((uint64_t)(hrow >> 6) * Vt + (v >> 6)) * 4096 +
                  ((v >> 3) & 7) * 512 + o * 8 + (v & 7)) = pk;
      }
    }
  }
}

// ---------------------------------------------------------------------------
// out[n][b][j] = max(H1p[b*64+j][1024+n], H2p[b*64+j][n]); packed H reads.
// ---------------------------------------------------------------------------
__global__ __launch_bounds__(256) void k_maxout(const unsigned short* __restrict__ H1,
                                                const unsigned short* __restrict__ H2,
                                                float* __restrict__ out) {
  __shared__ __align__(16) float tile[64 * 65];  // [j][n]
  const int t = threadIdx.x;
  const int b = blockIdx.y;
  const int n0 = blockIdx.x * 64;
  {
    int j = t >> 2, p = t & 3;
    int c1 = 1024 + n0 + p * 16;   // H1 col (Kt 48)
    int c2 = n0 + p * 16;          // H2 col (Kt 16)
    const unsigned short* h1p =
        H1 + ((uint64_t)b * 48 + (c1 >> 6)) * 4096 + ((c1 >> 3) & 7) * 512 + j * 8;
    const unsigned short* h2p =
        H2 + ((uint64_t)b * 16 + (c2 >> 6)) * 4096 + ((c2 >> 3) & 7) * 512 + j * 8;
    u16x8 a0 = *(const u16x8*)(h1p);
    u16x8 a1 = *(const u16x8*)(h1p + 512);
    u16x8 c0 = *(const u16x8*)(h2p);
    u16x8 c1v = *(const u16x8*)(h2p + 512);
#pragma unroll
    for (int u = 0; u < 8; ++u) {
      tile[j * 65 + p * 16 + u] = fmaxf(bf2f(a0[u]), bf2f(c0[u]));
      tile[j * 65 + p * 16 + 8 + u] = fmaxf(bf2f(a1[u]), bf2f(c1v[u]));
    }
  }
  __syncthreads();
  {
    int n = t >> 2, jb = (t & 3) * 16;
    float* op = out + (uint64_t)(n0 + n) * 4096 + b * 64 + jb;
#pragma unroll
    for (int q = 0; q < 4; ++q) {
      f32x4 o;
#pragma unroll
      for (int u = 0; u < 4; ++u) o[u] = tile[(jb + q * 4 + u) * 65 + n];
      *(f32x4*)(op + q * 4) = o;
    }
  }
}

// ---------------------------------------------------------------------------
extern "C" void kernel_launch(void* const* d_in, const int* in_sizes, int n_in,
                              void* d_out, int out_size, void* d_ws, size_t ws_size,
                              hipStream_t stream) {
  (void)in_sizes; (void)n_in; (void)out_size; (void)ws_size;
  const void* x  = d_in[0];  // [3072][64][64]
  const void* A  = d_in[1];  // [3072][3072]
  const void* W0 = d_in[2];  // [128][64]
  const void* b0 = d_in[3];  // [128]
  const void* W1 = d_in[4];  // [128][64]
  const void* b1 = d_in[5];  // [128]
  float* out = (float*)d_out;  // [1024][64][64] fp32

  char* ws = (char*)d_ws;
  unsigned short* Xtp = (unsigned short*)(ws + 0);         // 25165824 B (dead after K1f)
  unsigned short* H2p = (unsigned short*)(ws + 0);         // 8388608 B (overlay)
  unsigned short* Abp = (unsigned short*)(ws + 25165824);  // 18874368 B
  unsigned short* Wb  = (unsigned short*)(ws + 44040192);  // 33280 B
  unsigned short* H1p = (unsigned short*)(ws + 44105728);  // 25165824 B -> end 69271552
  int* flag = (int*)(ws + 69271552);

  k_detect<<<1, 64, 0, stream>>>((const uint32_t*)x, flag);
  k_transpose<<<dim3(48, 64), 256, 0, stream>>>(x, Xtp, flag);
  k_packA<<<dim3(48, 48), 256, 0, stream>>>(A, Abp, flag);
  k_cvtW<<<1, 256, 0, stream>>>(W0, b0, W1, b1, Wb, flag);
  // K1f: H1 = GLU(W0.(A.Xt^T)+b0), v covers 3072
  k_gemm_glu<128><<<dim3(24, 32), 256, 0, stream>>>(Abp, Xtp, Wb, Wb + 8192, H1p, 3072, 3072);
  // K3f: H2 = GLU(W1.(A[rows 1024+].H1^T)+b1), middle third (A row-tile offset 16)
  k_gemm_glu<64><<<dim3(16, 32), 256, 0, stream>>>(Abp + (uint64_t)16 * 48 * 4096, H1p,
                                                    Wb + 8320, Wb + 16512, H2p, 3072, 1024);
  k_maxout<<<dim3(16, 64), 256, 0, stream>>>(H1p, H2p, out);
}